// Round 6
// baseline (480.833 us; speedup 1.0000x reference)
//
#include <hip/hip_runtime.h>
#include <hip/hip_bf16.h>
#include <hip/hip_fp16.h>

#define HEADS 8
#define BB 32
#define CC 512
#define NN 1024   // tokens
#define DD 64     // head dim

typedef _Float16 f16;
typedef __attribute__((ext_vector_type(8))) _Float16 f16x8;
typedef __attribute__((ext_vector_type(4))) _Float16 f16x4;
typedef __attribute__((ext_vector_type(2))) __fp16 hf16x2;   // cvt_pkrtz native type
typedef __attribute__((ext_vector_type(4))) float f32x4;

// async global->LDS, 16B per lane; LDS dest is wave-uniform base + lane*16,
// global src is per-lane (m97/m173 pattern).
__device__ __forceinline__ void gload16(const f16* g, f16* l) {
    __builtin_amdgcn_global_load_lds(
        (const __attribute__((address_space(1))) void*)g,
        (__attribute__((address_space(3))) void*)l, 16, 0, 0);
}

// wave-local LDS drain + compiler fence (verified pattern from attn R8).
__device__ __forceinline__ void wavefence() {
    asm volatile("s_waitcnt lgkmcnt(0)" ::: "memory");
}

// ---------------------------------------------------------------------------
// wconv: W fp32 [3C][C] -> Wh fp16 (one-time, ~1.5 MB)
// ---------------------------------------------------------------------------
__global__ __launch_bounds__(256) void wconv(
    const float* __restrict__ W, f16* __restrict__ Wh)
{
    const size_t i = ((size_t)blockIdx.x * 256 + threadIdx.x) * 8;
    float4 a = *(const float4*)(W + i);
    float4 b = *(const float4*)(W + i + 4);
    f16x8 h = {(f16)a.x, (f16)a.y, (f16)a.z, (f16)a.w,
               (f16)b.x, (f16)b.y, (f16)b.z, (f16)b.w};
    *(f16x8*)(Wh + i) = h;
}

// ---------------------------------------------------------------------------
// prep_x: xt[b][m][c] fp16  <-  x[b][c][m] fp32   (LDS 64x64 transpose)
// ---------------------------------------------------------------------------
__global__ __launch_bounds__(256) void prep_x(
    const float* __restrict__ x, f16* __restrict__ xt)
{
    __shared__ f16 T[64][65];
    const int tid = threadIdx.x;
    const int c0 = blockIdx.x * 64;
    const int m0 = blockIdx.y * 64;
    const int b  = blockIdx.z;
    const float* xb = x + (size_t)b * CC * NN;

    const int m_l = tid & 63, c_l = tid >> 6;
    #pragma unroll
    for (int s = 0; s < 16; ++s) {
        const int cr = s * 4 + c_l;
        T[cr][m_l] = (f16)xb[(size_t)(c0 + cr) * NN + m0 + m_l];
    }
    __syncthreads();
    const int m_r = tid >> 2, cq = (tid & 3) * 16;
    f16 buf[16];
    #pragma unroll
    for (int j = 0; j < 16; ++j) buf[j] = T[cq + j][m_r];
    f16* dst = xt + ((size_t)b * NN + m0 + m_r) * CC + c0 + cq;
    *(f16x8*)dst       = *(f16x8*)&buf[0];
    *(f16x8*)(dst + 8) = *(f16x8*)&buf[8];
}

// ---------------------------------------------------------------------------
// qkv_mfma R10 (unchanged): gload_lds staging + LDS-transposed epilogue.
// Q pre-scaled by log2(e) (attn softmax runs in exp2 domain).
// ---------------------------------------------------------------------------
__global__ __launch_bounds__(256) void qkv_mfma(
    const f16*  __restrict__ xt,     // [B*N][C]
    const f16*  __restrict__ Wh,     // [3C][C]
    const float* __restrict__ h_pos, // [L][C]
    const float* __restrict__ w_pos, // [L][C]
    f16* __restrict__ Qh, f16* __restrict__ Kh, f16* __restrict__ Vt)
{
    __shared__ f16 SM[2 * 128 * 64];   // Xs | Ws, reused as epilogue scratch
    f16* Xs = SM;
    f16* Ws = SM + 128 * 64;

    const int tid  = threadIdx.x;
    const int wave = tid >> 6, lane = tid & 63;
    const int ln = lane & 15, quad = lane >> 4;

    // XCD swizzle: grid 3072 = 8 XCDs x 32 m-tiles x 12 o-tiles.
    const unsigned bid  = blockIdx.x;
    const unsigned xcd  = bid & 7;
    const unsigned slot = bid >> 3;            // 0..383
    const unsigned ot   = slot % 12u;
    const unsigned mt   = xcd * 32u + slot / 12u;
    const int o0  = (int)ot * 128;
    const int mg0 = (int)mt * 128;
    const int mw = (wave & 1) * 64, ow = (wave >> 1) * 64;

    f32x4 acc[4][4];
    #pragma unroll
    for (int ia = 0; ia < 4; ++ia)
        #pragma unroll
        for (int ib = 0; ib < 4; ++ib) acc[ia][ib] = (f32x4){0.f, 0.f, 0.f, 0.f};

    const int sr = wave * 32 + (lane >> 3);
    const int sc = (lane & 7) * 8;
    const f16* xg = xt + (size_t)(mg0 + sr) * CC + sc;
    const f16* wg = Wh + (size_t)(o0  + sr) * CC + sc;
    f16* xl = &Xs[(wave * 32) * 64];
    f16* wl = &Ws[(wave * 32) * 64];

    for (int ct = 0; ct < 8; ++ct) {
        const int c0 = ct * 64;
        __syncthreads();
        #pragma unroll
        for (int i = 0; i < 4; ++i) {
            gload16(xg + (size_t)i * 8 * CC + c0, xl + i * 8 * 64);
            gload16(wg + (size_t)i * 8 * CC + c0, wl + i * 8 * 64);
        }
        __syncthreads();   // drains vmcnt(0): tile visible
        #pragma unroll
        for (int ks = 0; ks < 2; ++ks) {
            f16x8 a[4], bf[4];
            #pragma unroll
            for (int f = 0; f < 4; ++f) {
                a[f]  = *(const f16x8*)&Xs[(mw + f * 16 + ln) * 64 + ks * 32 + quad * 8];
                bf[f] = *(const f16x8*)&Ws[(ow + f * 16 + ln) * 64 + ks * 32 + quad * 8];
            }
            #pragma unroll
            for (int ia = 0; ia < 4; ++ia)
                #pragma unroll
                for (int ib = 0; ib < 4; ++ib)
                    acc[ia][ib] = __builtin_amdgcn_mfma_f32_16x16x32_f16(
                        a[ia], bf[ib], acc[ia][ib], 0, 0, 0);
        }
    }

    __syncthreads();   // all waves done with Xs/Ws; safe to reuse as scratch
    f16* Ep = SM + wave * 4096;   // 8 KB per wave

    const int region = o0 >> 9;             // 0=Q, 1=K, 2=V
    const int ob = o0 + ow;
    const int p  = (ob >> 6) & 7;
    const int b  = mg0 >> 10;
    const int n0 = (mg0 & 1023) + mw;

    if (region < 2) {
        f16* dst = (region == 0) ? Qh : Kh;
        const size_t hb = (size_t)(b * HEADS + p) * NN * DD;
        #pragma unroll
        for (int ph = 0; ph < 2; ++ph) {
            #pragma unroll
            for (int ibl = 0; ibl < 2; ++ibl) {
                const int ib = ph * 2 + ibl;
                const int d  = ib * 16 + ln;
                const int dl = ibl * 16 + ln;
                #pragma unroll
                for (int ia = 0; ia < 4; ++ia) {
                    #pragma unroll
                    for (int r = 0; r < 4; ++r) {
                        const int nl = ia * 16 + quad * 4 + r;
                        float v = acc[ia][ib][r];
                        if (region == 0) {
                            v *= 1.44269504f;   // log2(e): attn softmax in exp2 domain
                        } else {
                            const int n = n0 + nl;
                            const int c = p * DD + d;
                            v += h_pos[(n >> 5) * CC + c] + w_pos[(n & 31) * CC + c];
                        }
                        Ep[nl * 34 + dl] = (f16)v;
                    }
                }
            }
            wavefence();
            #pragma unroll
            for (int j = 0; j < 4; ++j) {
                const int nl = (lane >> 2) + 16 * j;
                const int dc = (lane & 3) * 8;
                f16x8 row = *(const f16x8*)&Ep[nl * 34 + dc];
                *(f16x8*)(dst + hb + (size_t)(n0 + nl) * DD + ph * 32 + dc) = row;
            }
            wavefence();
        }
    } else {
        const size_t vb = (size_t)(b * HEADS + p) * DD * NN;
        #pragma unroll
        for (int ph = 0; ph < 2; ++ph) {
            #pragma unroll
            for (int ibl = 0; ibl < 2; ++ibl) {
                const int ib = ph * 2 + ibl;
                const int dl = ibl * 16 + ln;
                #pragma unroll
                for (int ia = 0; ia < 4; ++ia) {
                    const int nl = ia * 16 + quad * 4;
                    f16x4 pk = {(f16)acc[ia][ib][0], (f16)acc[ia][ib][1],
                                (f16)acc[ia][ib][2], (f16)acc[ia][ib][3]};
                    *(f16x4*)&Ep[dl * 68 + nl] = pk;
                }
            }
            wavefence();
            #pragma unroll
            for (int j = 0; j < 4; ++j) {
                const int dl = (lane >> 3) + 8 * j;
                const int nc = (lane & 7) * 8;
                f16x8 row = *(const f16x8*)&Ep[dl * 68 + nc];
                *(f16x8*)(Vt + vb + (size_t)(ph * 32 + dl) * NN + n0 + nc) = row;
            }
            wavefence();
        }
    }
}

// ---------------------------------------------------------------------------
// attn_kernel R12: barrier-free, L2-direct K/V (common-mistake #7 fix).
// R11 post-mortem: q-blocking behind barriers collapsed occupancy ->
// latency-bound (occ 40->21, all pipes idle).  K/V per (b,p) = 256 KB and
// L2-hot after the XCD swizzle (FETCH 278->49 MB proved it), so the LDS
// staging + 2 barriers/kt existed only to serve a cache that L2 already is.
// Now: bk/vb fragments load DIRECTLY from global (16 rows x 64B segments,
// L2-resident); NO __syncthreads anywhere; LDS holds only wave-private P
// (lgkmcnt-fenced, R8-verified).  q-block 2x kept: halves frag traffic and
// is now free of barrier serialization.  Fragment layouts bitwise = R8/R11.
// ---------------------------------------------------------------------------
#define KST 76

__global__ __launch_bounds__(256) void attn_kernel(
    const f16* __restrict__ Qh, const f16* __restrict__ Kh,
    const f16* __restrict__ Vt, float* __restrict__ out)
{
    __shared__ f16 PS[4][32 * KST];

    const int tid  = threadIdx.x;
    const int wave = tid >> 6;
    const int lane = tid & 63;
    const int ln   = lane & 15;
    const int quad = lane >> 4;

    // XCD swizzle: grid 2048 = 8 XCDs x 32 (b,p)-groups x 8 qt.
    const unsigned bid  = blockIdx.x;
    const unsigned xcd  = bid & 7;
    const unsigned slot = bid >> 3;              // 0..255
    const int qt = (int)(slot & 7u);
    const unsigned g = xcd * 32u + (slot >> 3);  // 0..255
    const int b = (int)(g >> 3);
    const int p = (int)(g & 7u);
    const size_t hb = (size_t)(b * HEADS + p) * NN * DD;

    // Q fragments: 32 q-rows per wave, two 16-row frags (qa = 0,1).
    const int qbase = qt * 128 + wave * 32;
    f16x8 qf[2][2];
    #pragma unroll
    for (int qa = 0; qa < 2; ++qa)
        #pragma unroll
        for (int ks = 0; ks < 2; ++ks)
            qf[qa][ks] = *(const f16x8*)(
                Qh + hb + (size_t)(qbase + qa * 16 + ln) * DD + ks * 32 + quad * 8);

    // Per-lane frag base pointers (row = ln-dependent, k-chunk = quad-dependent).
    const f16* Kp = Kh + hb + (size_t)ln * DD + quad * 8;   // + (kt*64+nt*16)*DD + ks*32
    const f16* Vp = Vt + hb + (size_t)ln * NN + quad * 8;   // + dt*16*NN + kt*64 + ks*32

    // o[qa][dt][r] = O[q = qbase+qa*16+ln][d = dt*16 + quad*4 + r]
    f32x4 o[2][4];
    #pragma unroll
    for (int qa = 0; qa < 2; ++qa)
        #pragma unroll
        for (int dt = 0; dt < 4; ++dt) o[qa][dt] = (f32x4){0.f, 0.f, 0.f, 0.f};
    float lrun[2] = {0.f, 0.f};
    float mrun[2] = {-__builtin_inff(), -__builtin_inff()};
    const float THR = 11.5416f;   // 8 nats in log2 units

    f16* Pw = &PS[wave][0];

    for (int kt = 0; kt < 16; ++kt) {
        // --- QK^T: K fragments straight from L2 (8 independent 16B loads) ---
        f16x8 bk[2][4];
        #pragma unroll
        for (int ks = 0; ks < 2; ++ks)
            #pragma unroll
            for (int nt = 0; nt < 4; ++nt)
                bk[ks][nt] = *(const f16x8*)(
                    Kp + (size_t)(kt * 64 + nt * 16) * DD + ks * 32);

        f32x4 s[2][4];
        #pragma unroll
        for (int qa = 0; qa < 2; ++qa)
            #pragma unroll
            for (int nt = 0; nt < 4; ++nt) s[qa][nt] = (f32x4){0.f, 0.f, 0.f, 0.f};
        #pragma unroll
        for (int ks = 0; ks < 2; ++ks) {
            #pragma unroll
            for (int nt = 0; nt < 4; ++nt) {
                s[0][nt] = __builtin_amdgcn_mfma_f32_16x16x32_f16(bk[ks][nt], qf[0][ks], s[0][nt], 0, 0, 0);
                s[1][nt] = __builtin_amdgcn_mfma_f32_16x16x32_f16(bk[ks][nt], qf[1][ks], s[1][nt], 0, 0, 0);
            }
        }

        // Row max per qa: 15 in-reg fmax + 2 cross-quad shuffles.
        float mx[2];
        #pragma unroll
        for (int qa = 0; qa < 2; ++qa) {
            float m0 = s[qa][0][0];
            #pragma unroll
            for (int nt = 0; nt < 4; ++nt)
                #pragma unroll
                for (int r = 0; r < 4; ++r) m0 = fmaxf(m0, s[qa][nt][r]);
            m0 = fmaxf(m0, __shfl_xor(m0, 16));
            m0 = fmaxf(m0, __shfl_xor(m0, 32));
            mx[qa] = m0;
        }

        // T13 defer-max (joint over both q-frags, keeps branch wave-uniform).
        if (__any(mx[0] > mrun[0] + THR || mx[1] > mrun[1] + THR)) {
            #pragma unroll
            for (int qa = 0; qa < 2; ++qa) {
                const float mnew = fmaxf(mrun[qa], mx[qa]);
                const float alpha = __builtin_amdgcn_exp2f(mrun[qa] - mnew);
                mrun[qa] = mnew;
                lrun[qa] *= alpha;
                #pragma unroll
                for (int dt = 0; dt < 4; ++dt) {
                    o[qa][dt][0] *= alpha; o[qa][dt][1] *= alpha;
                    o[qa][dt][2] *= alpha; o[qa][dt][3] *= alpha;
                }
            }
        }

        // P = exp2(S-m): fp32 row-sums in regs, packed f16 to wave-private LDS.
        #pragma unroll
        for (int qa = 0; qa < 2; ++qa) {
            float lsum = 0.f;
            #pragma unroll
            for (int nt = 0; nt < 4; ++nt) {
                const float p0 = __builtin_amdgcn_exp2f(s[qa][nt][0] - mrun[qa]);
                const float p1 = __builtin_amdgcn_exp2f(s[qa][nt][1] - mrun[qa]);
                const float p2 = __builtin_amdgcn_exp2f(s[qa][nt][2] - mrun[qa]);
                const float p3 = __builtin_amdgcn_exp2f(s[qa][nt][3] - mrun[qa]);
                lsum += (p0 + p1) + (p2 + p3);
                hf16x2 lo = __builtin_amdgcn_cvt_pkrtz(p0, p1);
                hf16x2 hi = __builtin_amdgcn_cvt_pkrtz(p2, p3);
                f16x4 pk = {(f16)lo.x, (f16)lo.y, (f16)hi.x, (f16)hi.y};
                *(f16x4*)&Pw[(qa * 16 + ln) * KST + nt * 16 + quad * 4] = pk;
            }
            lsum += __shfl_xor(lsum, 16);
            lsum += __shfl_xor(lsum, 32);
            lrun[qa] += lsum;
        }

        // PS is wave-private: wave-local LDS drain (no __syncthreads anywhere).
        wavefence();

        // --- PV: V^T fragments straight from L2; frags shared by both qa ---
        #pragma unroll
        for (int ks = 0; ks < 2; ++ks) {
            f16x8 pa0 = *(const f16x8*)&Pw[(ln)      * KST + ks * 32 + quad * 8];
            f16x8 pa1 = *(const f16x8*)&Pw[(16 + ln) * KST + ks * 32 + quad * 8];
            #pragma unroll
            for (int dt = 0; dt < 4; ++dt) {
                f16x8 vb = *(const f16x8*)(
                    Vp + (size_t)(dt * 16) * NN + kt * 64 + ks * 32);
                o[0][dt] = __builtin_amdgcn_mfma_f32_16x16x32_f16(vb, pa0, o[0][dt], 0, 0, 0);
                o[1][dt] = __builtin_amdgcn_mfma_f32_16x16x32_f16(vb, pa1, o[1][dt], 0, 0, 0);
            }
        }
    }

    // Epilogue: lane holds O[q][d = dt*16+quad*4+r] for q = qbase+qa*16+ln.
    #pragma unroll
    for (int qa = 0; qa < 2; ++qa) {
        const float inv = 1.0f / lrun[qa];
        const int nq = qbase + qa * 16 + ln;
        #pragma unroll
        for (int dt = 0; dt < 4; ++dt) {
            const int c = p * DD + dt * 16 + quad * 4;
            #pragma unroll
            for (int r = 0; r < 4; ++r)
                out[((size_t)b * CC + c + r) * NN + nq] = o[qa][dt][r] * inv;
        }
    }
}

extern "C" void kernel_launch(void* const* d_in, const int* in_sizes, int n_in,
                              void* d_out, int out_size, void* d_ws, size_t ws_size,
                              hipStream_t stream) {
    const float* x     = (const float*)d_in[0];
    const float* qkv_w = (const float*)d_in[1];
    const float* h_pos = (const float*)d_in[2];
    const float* w_pos = (const float*)d_in[3];
    float* out = (float*)d_out;

    const size_t PT = (size_t)BB * HEADS * NN * DD;  // 16,777,216 elems
    f16* xt = (f16*)d_ws;
    f16* Qh = xt + PT;
    f16* Kh = Qh + PT;
    f16* Vt = Kh + PT;
    f16* Wh = Vt + PT;   // 3C*C = 786,432 f16; total ~135.7 MB (fits)

    wconv<<<dim3(3 * CC * CC / (256 * 8)), 256, 0, stream>>>(qkv_w, Wh);
    prep_x<<<dim3(CC / 64, NN / 64, BB), 256, 0, stream>>>(x, xt);
    qkv_mfma<<<dim3(3072), 256, 0, stream>>>(xt, Wh, h_pos, w_pos, Qh, Kh, Vt);
    attn_kernel<<<dim3(2048), 256, 0, stream>>>(Qh, Kh, Vt, out);
}

// Round 8
// 357.474 us; speedup vs baseline: 1.3451x; 1.3451x over previous
//
#include <hip/hip_runtime.h>
#include <hip/hip_bf16.h>
#include <hip/hip_fp16.h>

#define HEADS 8
#define BB 32
#define CC 512
#define NN 1024   // tokens
#define DD 64     // head dim

typedef _Float16 f16;
typedef __attribute__((ext_vector_type(8))) _Float16 f16x8;
typedef __attribute__((ext_vector_type(4))) _Float16 f16x4;
typedef __attribute__((ext_vector_type(2))) __fp16 hf16x2;   // cvt_pkrtz native type
typedef __attribute__((ext_vector_type(4))) float f32x4;
typedef __attribute__((ext_vector_type(16))) float f32x16;
typedef __attribute__((ext_vector_type(4))) unsigned u32x4;

// async global->LDS, 16B per lane (m97/m173 pattern).
__device__ __forceinline__ void gload16(const f16* g, f16* l) {
    __builtin_amdgcn_global_load_lds(
        (const __attribute__((address_space(1))) void*)g,
        (__attribute__((address_space(3))) void*)l, 16, 0, 0);
}

__device__ __forceinline__ void wavefence() {
    asm volatile("s_waitcnt lgkmcnt(0)" ::: "memory");
}

// v_permlane32_swap_b32 via the SSA-clean builtin (R13 bug: inline-asm "+v"
// with two equal-valued operands let the allocator alias them to ONE register,
// turning the swap into an in-place half-exchange -> broken max/sum reduce).
// Semantics: exchanges a's upper 32 lanes with b's lower 32 lanes:
//   a' = [a_lo | b_lo],  b' = [a_hi | b_hi].
__device__ __forceinline__ void pl32swap(unsigned &a, unsigned &b) {
    auto r = __builtin_amdgcn_permlane32_swap(a, b, false, false);
    a = r[0]; b = r[1];
}

// cross-half (lane ^ 32) max / sum: zero DS ops.
__device__ __forceinline__ float xhalf_max(float x) {
    unsigned a = __float_as_uint(x), b = a;
    pl32swap(a, b);   // a' = [x_lo|x_lo], b' = [x_hi|x_hi] -> max is cross-half
    return fmaxf(__uint_as_float(a), __uint_as_float(b));
}
__device__ __forceinline__ float xhalf_sum(float x) {
    unsigned a = __float_as_uint(x), b = a;
    pl32swap(a, b);
    return __uint_as_float(a) + __uint_as_float(b);
}

// ---------------------------------------------------------------------------
// wconv: W fp32 [3C][C] -> Wh fp16 (one-time, ~1.5 MB)
// ---------------------------------------------------------------------------
__global__ __launch_bounds__(256) void wconv(
    const float* __restrict__ W, f16* __restrict__ Wh)
{
    const size_t i = ((size_t)blockIdx.x * 256 + threadIdx.x) * 8;
    float4 a = *(const float4*)(W + i);
    float4 b = *(const float4*)(W + i + 4);
    f16x8 h = {(f16)a.x, (f16)a.y, (f16)a.z, (f16)a.w,
               (f16)b.x, (f16)b.y, (f16)b.z, (f16)b.w};
    *(f16x8*)(Wh + i) = h;
}

// ---------------------------------------------------------------------------
// prep_x: xt[b][m][c] fp16  <-  x[b][c][m] fp32   (LDS 64x64 transpose)
// ---------------------------------------------------------------------------
__global__ __launch_bounds__(256) void prep_x(
    const float* __restrict__ x, f16* __restrict__ xt)
{
    __shared__ f16 T[64][65];
    const int tid = threadIdx.x;
    const int c0 = blockIdx.x * 64;
    const int m0 = blockIdx.y * 64;
    const int b  = blockIdx.z;
    const float* xb = x + (size_t)b * CC * NN;

    const int m_l = tid & 63, c_l = tid >> 6;
    #pragma unroll
    for (int s = 0; s < 16; ++s) {
        const int cr = s * 4 + c_l;
        T[cr][m_l] = (f16)xb[(size_t)(c0 + cr) * NN + m0 + m_l];
    }
    __syncthreads();
    const int m_r = tid >> 2, cq = (tid & 3) * 16;
    f16 buf[16];
    #pragma unroll
    for (int j = 0; j < 16; ++j) buf[j] = T[cq + j][m_r];
    f16* dst = xt + ((size_t)b * NN + m0 + m_r) * CC + c0 + cq;
    *(f16x8*)dst       = *(f16x8*)&buf[0];
    *(f16x8*)(dst + 8) = *(f16x8*)&buf[8];
}

// ---------------------------------------------------------------------------
// qkv_mfma R10 (unchanged, verified): gload_lds staging + LDS epilogue.
// Q pre-scaled by log2(e) (attn softmax runs in exp2 domain).
// ---------------------------------------------------------------------------
__global__ __launch_bounds__(256) void qkv_mfma(
    const f16*  __restrict__ xt,     // [B*N][C]
    const f16*  __restrict__ Wh,     // [3C][C]
    const float* __restrict__ h_pos, // [L][C]
    const float* __restrict__ w_pos, // [L][C]
    f16* __restrict__ Qh, f16* __restrict__ Kh, f16* __restrict__ Vt)
{
    __shared__ f16 SM[2 * 128 * 64];   // Xs | Ws, reused as epilogue scratch
    f16* Xs = SM;
    f16* Ws = SM + 128 * 64;

    const int tid  = threadIdx.x;
    const int wave = tid >> 6, lane = tid & 63;
    const int ln = lane & 15, quad = lane >> 4;

    const unsigned bid  = blockIdx.x;
    const unsigned xcd  = bid & 7;
    const unsigned slot = bid >> 3;            // 0..383
    const unsigned ot   = slot % 12u;
    const unsigned mt   = xcd * 32u + slot / 12u;
    const int o0  = (int)ot * 128;
    const int mg0 = (int)mt * 128;
    const int mw = (wave & 1) * 64, ow = (wave >> 1) * 64;

    f32x4 acc[4][4];
    #pragma unroll
    for (int ia = 0; ia < 4; ++ia)
        #pragma unroll
        for (int ib = 0; ib < 4; ++ib) acc[ia][ib] = (f32x4){0.f, 0.f, 0.f, 0.f};

    const int sr = wave * 32 + (lane >> 3);
    const int sc = (lane & 7) * 8;
    const f16* xg = xt + (size_t)(mg0 + sr) * CC + sc;
    const f16* wg = Wh + (size_t)(o0  + sr) * CC + sc;
    f16* xl = &Xs[(wave * 32) * 64];
    f16* wl = &Ws[(wave * 32) * 64];

    for (int ct = 0; ct < 8; ++ct) {
        const int c0 = ct * 64;
        __syncthreads();
        #pragma unroll
        for (int i = 0; i < 4; ++i) {
            gload16(xg + (size_t)i * 8 * CC + c0, xl + i * 8 * 64);
            gload16(wg + (size_t)i * 8 * CC + c0, wl + i * 8 * 64);
        }
        __syncthreads();   // drains vmcnt(0): tile visible
        #pragma unroll
        for (int ks = 0; ks < 2; ++ks) {
            f16x8 a[4], bf[4];
            #pragma unroll
            for (int f = 0; f < 4; ++f) {
                a[f]  = *(const f16x8*)&Xs[(mw + f * 16 + ln) * 64 + ks * 32 + quad * 8];
                bf[f] = *(const f16x8*)&Ws[(ow + f * 16 + ln) * 64 + ks * 32 + quad * 8];
            }
            #pragma unroll
            for (int ia = 0; ia < 4; ++ia)
                #pragma unroll
                for (int ib = 0; ib < 4; ++ib)
                    acc[ia][ib] = __builtin_amdgcn_mfma_f32_16x16x32_f16(
                        a[ia], bf[ib], acc[ia][ib], 0, 0, 0);
        }
    }

    __syncthreads();   // all waves done with Xs/Ws; safe to reuse as scratch
    f16* Ep = SM + wave * 4096;   // 8 KB per wave

    const int region = o0 >> 9;             // 0=Q, 1=K, 2=V
    const int ob = o0 + ow;
    const int p  = (ob >> 6) & 7;
    const int b  = mg0 >> 10;
    const int n0 = (mg0 & 1023) + mw;

    if (region < 2) {
        f16* dst = (region == 0) ? Qh : Kh;
        const size_t hb = (size_t)(b * HEADS + p) * NN * DD;
        #pragma unroll
        for (int ph = 0; ph < 2; ++ph) {
            #pragma unroll
            for (int ibl = 0; ibl < 2; ++ibl) {
                const int ib = ph * 2 + ibl;
                const int d  = ib * 16 + ln;
                const int dl = ibl * 16 + ln;
                #pragma unroll
                for (int ia = 0; ia < 4; ++ia) {
                    #pragma unroll
                    for (int r = 0; r < 4; ++r) {
                        const int nl = ia * 16 + quad * 4 + r;
                        float v = acc[ia][ib][r];
                        if (region == 0) {
                            v *= 1.44269504f;   // log2(e)
                        } else {
                            const int n = n0 + nl;
                            const int c = p * DD + d;
                            v += h_pos[(n >> 5) * CC + c] + w_pos[(n & 31) * CC + c];
                        }
                        Ep[nl * 34 + dl] = (f16)v;
                    }
                }
            }
            wavefence();
            #pragma unroll
            for (int j = 0; j < 4; ++j) {
                const int nl = (lane >> 2) + 16 * j;
                const int dc = (lane & 3) * 8;
                f16x8 row = *(const f16x8*)&Ep[nl * 34 + dc];
                *(f16x8*)(dst + hb + (size_t)(n0 + nl) * DD + ph * 32 + dc) = row;
            }
            wavefence();
        }
    } else {
        const size_t vb = (size_t)(b * HEADS + p) * DD * NN;
        #pragma unroll
        for (int ph = 0; ph < 2; ++ph) {
            #pragma unroll
            for (int ibl = 0; ibl < 2; ++ibl) {
                const int ib = ph * 2 + ibl;
                const int dl = ibl * 16 + ln;
                #pragma unroll
                for (int ia = 0; ia < 4; ++ia) {
                    const int nl = ia * 16 + quad * 4;
                    f16x4 pk = {(f16)acc[ia][ib][0], (f16)acc[ia][ib][1],
                                (f16)acc[ia][ib][2], (f16)acc[ia][ib][3]};
                    *(f16x4*)&Ep[dl * 68 + nl] = pk;
                }
            }
            wavefence();
            #pragma unroll
            for (int j = 0; j < 4; ++j) {
                const int dl = (lane >> 3) + 8 * j;
                const int nc = (lane & 7) * 8;
                f16x8 row = *(const f16x8*)&Ep[dl * 68 + nc];
                *(f16x8*)(Vt + vb + (size_t)(ph * 32 + dl) * NN + n0 + nc) = row;
            }
            wavefence();
        }
    }
}

// ---------------------------------------------------------------------------
// attn_kernel R14 = R13 (32x32x16 MFMA, in-register P via permlane) with the
// permlane aliasing bug fixed (builtin instead of inline asm).
// Layouts (all derived, lane-checked):
//  * QK^T swapped: sA/sB = S^T[key][q], C col = q = lane&31 (lane-local q),
//    row = key = (reg&3)+8*(reg>>2)+4*(lane>>5)  [guide m74/m101].
//  * P redistribution per 16-key step s: cvt_pkrtz pairs; 2 pl32swap deliver
//    B[k=8h+j][q=l31] = keys 16s+8h+{0..7}.  Zero DS for P.
//  * Softmax reduce: 31 in-reg fmax + 1 permlane swap (max), same for sum.
// ---------------------------------------------------------------------------
#define KST 76

__global__ __launch_bounds__(128) void attn_kernel(
    const f16* __restrict__ Qh, const f16* __restrict__ Kh,
    const f16* __restrict__ Vt, float* __restrict__ out)
{
    __shared__ f16 KS [64 * KST];
    __shared__ f16 VtS[64 * KST];

    const int tid  = threadIdx.x;
    const int wave = tid >> 6;          // 0..1
    const int lane = tid & 63;
    const int l31  = lane & 31;
    const int h    = lane >> 5;

    // XCD swizzle: grid 4096 = 8 XCDs x 32 (b,p)-groups x 16 qt (= R10).
    const unsigned bid  = blockIdx.x;
    const unsigned xcd  = bid & 7;
    const unsigned slot = bid >> 3;              // 0..511
    const int qt = (int)(slot & 15u);
    const unsigned g = xcd * 32u + (slot >> 4);  // 0..255
    const int b = (int)(g >> 3);
    const int p = (int)(g & 7u);
    const size_t hb = (size_t)(b * HEADS + p) * NN * DD;

    // Q B-frags: col q = l31, k = 16s + 8h + j  (4 frags cover d=64).
    const int qbase = qt * 64 + wave * 32;
    f16x8 qf[4];
    #pragma unroll
    for (int s = 0; s < 4; ++s)
        qf[s] = *(const f16x8*)(Qh + hb + (size_t)(qbase + l31) * DD + s * 16 + h * 8);

    // O accumulators: C[row=d][col=q]; oA: d 0..31, oB: d 32..63.
    f32x16 oA = {0.f,0.f,0.f,0.f,0.f,0.f,0.f,0.f,0.f,0.f,0.f,0.f,0.f,0.f,0.f,0.f};
    f32x16 oB = oA;
    float lrun = 0.f;
    float mrun = -__builtin_inff();
    const float THR = 11.5416f;   // 8 nats in log2 units

    // Staging: thread covers row tr = tid>>1, 32-col half tc = (tid&1)*32.
    const int tr = tid >> 1, tc = (tid & 1) * 32;
    f16x8 kr[4], vr[4];
    #pragma unroll
    for (int k = 0; k < 4; ++k) {
        kr[k] = *(const f16x8*)(Kh + hb + (size_t)tr * DD + tc + k * 8);
        vr[k] = *(const f16x8*)(Vt + hb + (size_t)tr * NN + tc + k * 8);
    }

    for (int kt = 0; kt < 16; ++kt) {
        __syncthreads();   // B1
        #pragma unroll
        for (int k = 0; k < 4; ++k) {
            *(f16x8*)&KS [tr * KST + tc + k * 8] = kr[k];
            *(f16x8*)&VtS[tr * KST + tc + k * 8] = vr[k];
        }
        if (kt < 15) {   // T14: next-tile loads in flight across compute
            #pragma unroll
            for (int k = 0; k < 4; ++k) {
                kr[k] = *(const f16x8*)(Kh + hb + (size_t)((kt + 1) * 64 + tr) * DD + tc + k * 8);
                vr[k] = *(const f16x8*)(Vt + hb + (size_t)tr * NN + (kt + 1) * 64 + tc + k * 8);
            }
        }
        __syncthreads();   // B2

        // QK^T: sA = S^T[keys 0..31][q], sB = [keys 32..63][q]  (log2 domain)
        f32x16 sA = {0.f,0.f,0.f,0.f,0.f,0.f,0.f,0.f,0.f,0.f,0.f,0.f,0.f,0.f,0.f,0.f};
        f32x16 sB = sA;
        #pragma unroll
        for (int s = 0; s < 4; ++s) {
            f16x8 a0 = *(const f16x8*)&KS[(l31)      * KST + s * 16 + h * 8];
            f16x8 a1 = *(const f16x8*)&KS[(32 + l31) * KST + s * 16 + h * 8];
            sA = __builtin_amdgcn_mfma_f32_32x32x16_f16(a0, qf[s], sA, 0, 0, 0);
            sB = __builtin_amdgcn_mfma_f32_32x32x16_f16(a1, qf[s], sB, 0, 0, 0);
        }

        // Row max for q=l31: 31 in-reg fmax + 1 cross-half permlane swap.
        float mx = sA[0];
        #pragma unroll
        for (int i = 1; i < 16; ++i) mx = fmaxf(mx, sA[i]);
        #pragma unroll
        for (int i = 0; i < 16; ++i) mx = fmaxf(mx, sB[i]);
        mx = xhalf_max(mx);

        // T13 defer-max.
        if (__any(mx > mrun + THR)) {
            const float mnew = fmaxf(mrun, mx);
            const float alpha = __builtin_amdgcn_exp2f(mrun - mnew);  // 0 first tile
            mrun = mnew;
            lrun *= alpha;
            #pragma unroll
            for (int i = 0; i < 16; ++i) { oA[i] *= alpha; oB[i] *= alpha; }
        }

        // PV: 4 steps of 16 keys; P built in-register (T12), zero DS for P.
        float lsum = 0.f;
        #pragma unroll
        for (int s = 0; s < 4; ++s) {
            const f32x16& sk = (s < 2) ? sA : sB;
            const int base = (s & 1) * 8;
            const float e0 = __builtin_amdgcn_exp2f(sk[base + 0] - mrun);
            const float e1 = __builtin_amdgcn_exp2f(sk[base + 1] - mrun);
            const float e2 = __builtin_amdgcn_exp2f(sk[base + 2] - mrun);
            const float e3 = __builtin_amdgcn_exp2f(sk[base + 3] - mrun);
            const float e4 = __builtin_amdgcn_exp2f(sk[base + 4] - mrun);
            const float e5 = __builtin_amdgcn_exp2f(sk[base + 5] - mrun);
            const float e6 = __builtin_amdgcn_exp2f(sk[base + 6] - mrun);
            const float e7 = __builtin_amdgcn_exp2f(sk[base + 7] - mrun);
            lsum += ((e0 + e1) + (e2 + e3)) + ((e4 + e5) + (e6 + e7));
            unsigned d00 = __builtin_bit_cast(unsigned, __builtin_amdgcn_cvt_pkrtz(e0, e1));
            unsigned d01 = __builtin_bit_cast(unsigned, __builtin_amdgcn_cvt_pkrtz(e2, e3));
            unsigned d10 = __builtin_bit_cast(unsigned, __builtin_amdgcn_cvt_pkrtz(e4, e5));
            unsigned d11 = __builtin_bit_cast(unsigned, __builtin_amdgcn_cvt_pkrtz(e6, e7));
            pl32swap(d00, d10);   // h=0: keys {0,1},{4,5}; h=1: {8,9},{12,13} (+16s)
            pl32swap(d01, d11);   // h=0: keys {2,3},{6,7}; h=1: {10,11},{14,15}
            u32x4 pu = {d00, d01, d10, d11};
            f16x8 pb = __builtin_bit_cast(f16x8, pu);   // B[k=8h+j][q=l31]
            f16x8 v0 = *(const f16x8*)&VtS[(l31)      * KST + s * 16 + h * 8];
            f16x8 v1 = *(const f16x8*)&VtS[(32 + l31) * KST + s * 16 + h * 8];
            oA = __builtin_amdgcn_mfma_f32_32x32x16_f16(v0, pb, oA, 0, 0, 0);
            oB = __builtin_amdgcn_mfma_f32_32x32x16_f16(v1, pb, oB, 0, 0, 0);
        }
        lrun += xhalf_sum(lsum);
    }

    // Epilogue: lane holds O[d][q=l31], d = dblk*32 + (reg&3)+8*(reg>>2)+4h.
    const float inv = 1.0f / lrun;
    const int nq = qbase + l31;
    float* ob = out + ((size_t)b * CC + p * DD) * NN + nq;
    #pragma unroll
    for (int reg = 0; reg < 16; ++reg) {
        const int dr = (reg & 3) + 8 * (reg >> 2) + 4 * h;
        ob[(size_t)dr * NN]        = oA[reg] * inv;
        ob[(size_t)(32 + dr) * NN] = oB[reg] * inv;
    }
}

extern "C" void kernel_launch(void* const* d_in, const int* in_sizes, int n_in,
                              void* d_out, int out_size, void* d_ws, size_t ws_size,
                              hipStream_t stream) {
    const float* x     = (const float*)d_in[0];
    const float* qkv_w = (const float*)d_in[1];
    const float* h_pos = (const float*)d_in[2];
    const float* w_pos = (const float*)d_in[3];
    float* out = (float*)d_out;

    const size_t PT = (size_t)BB * HEADS * NN * DD;  // 16,777,216 elems
    f16* xt = (f16*)d_ws;
    f16* Qh = xt + PT;
    f16* Kh = Qh + PT;
    f16* Vt = Kh + PT;
    f16* Wh = Vt + PT;   // 3C*C = 786,432 f16; total ~135.7 MB (fits)

    wconv<<<dim3(3 * CC * CC / (256 * 8)), 256, 0, stream>>>(qkv_w, Wh);
    prep_x<<<dim3(CC / 64, NN / 64, BB), 256, 0, stream>>>(x, xt);
    qkv_mfma<<<dim3(3072), 256, 0, stream>>>(xt, Wh, h_pos, w_pos, Qh, Kh, Vt);
    attn_kernel<<<dim3(4096), 128, 0, stream>>>(Qh, Kh, Vt, out);
}

// Round 9
// 342.405 us; speedup vs baseline: 1.4043x; 1.0440x over previous
//
#include <hip/hip_runtime.h>
#include <hip/hip_bf16.h>
#include <hip/hip_fp16.h>

#define HEADS 8
#define BB 32
#define CC 512
#define NN 1024   // tokens
#define DD 64     // head dim

typedef _Float16 f16;
typedef __attribute__((ext_vector_type(8))) _Float16 f16x8;
typedef __attribute__((ext_vector_type(4))) _Float16 f16x4;
typedef __attribute__((ext_vector_type(2))) __fp16 hf16x2;   // cvt_pkrtz native type
typedef __attribute__((ext_vector_type(4))) float f32x4;
typedef __attribute__((ext_vector_type(16))) float f32x16;
typedef __attribute__((ext_vector_type(4))) unsigned u32x4;

// async global->LDS, 16B per lane (m97/m173 pattern).
__device__ __forceinline__ void gload16(const f16* g, f16* l) {
    __builtin_amdgcn_global_load_lds(
        (const __attribute__((address_space(1))) void*)g,
        (__attribute__((address_space(3))) void*)l, 16, 0, 0);
}

__device__ __forceinline__ void wavefence() {
    asm volatile("s_waitcnt lgkmcnt(0)" ::: "memory");
}

// v_permlane32_swap_b32 via the SSA-clean builtin (R13 lesson: inline-asm "+v"
// with two equal-valued operands can alias to ONE register -> broken swap).
__device__ __forceinline__ void pl32swap(unsigned &a, unsigned &b) {
    auto r = __builtin_amdgcn_permlane32_swap(a, b, false, false);
    a = r[0]; b = r[1];
}

// cross-half (lane ^ 32) max / sum: zero DS ops.
__device__ __forceinline__ float xhalf_max(float x) {
    unsigned a = __float_as_uint(x), b = a;
    pl32swap(a, b);
    return fmaxf(__uint_as_float(a), __uint_as_float(b));
}
__device__ __forceinline__ float xhalf_sum(float x) {
    unsigned a = __float_as_uint(x), b = a;
    pl32swap(a, b);
    return __uint_as_float(a) + __uint_as_float(b);
}

// ---------------------------------------------------------------------------
// wconv: W fp32 [3C][C] -> Wh fp16 (one-time, ~1.5 MB)
// ---------------------------------------------------------------------------
__global__ __launch_bounds__(256) void wconv(
    const float* __restrict__ W, f16* __restrict__ Wh)
{
    const size_t i = ((size_t)blockIdx.x * 256 + threadIdx.x) * 8;
    float4 a = *(const float4*)(W + i);
    float4 b = *(const float4*)(W + i + 4);
    f16x8 h = {(f16)a.x, (f16)a.y, (f16)a.z, (f16)a.w,
               (f16)b.x, (f16)b.y, (f16)b.z, (f16)b.w};
    *(f16x8*)(Wh + i) = h;
}

// ---------------------------------------------------------------------------
// prep_x R15: float4 global reads (G13: 4 dwordx4 per thread instead of 16
// scalar dwords).  LDS stride 72 f16 (144B): 8B-aligned b64 writes.
// ---------------------------------------------------------------------------
__global__ __launch_bounds__(256) void prep_x(
    const float* __restrict__ x, f16* __restrict__ xt)
{
    __shared__ f16 T[64][72];
    const int tid = threadIdx.x;
    const int c0 = blockIdx.x * 64;
    const int m0 = blockIdx.y * 64;
    const int b  = blockIdx.z;
    const float* xb = x + (size_t)b * CC * NN;

    const int c_l = tid >> 4;          // 0..15
    const int m4  = (tid & 15) * 4;    // float4 column offset
    #pragma unroll
    for (int s = 0; s < 4; ++s) {
        const int cr = s * 16 + c_l;
        float4 v = *(const float4*)(xb + (size_t)(c0 + cr) * NN + m0 + m4);
        f16x4 h = {(f16)v.x, (f16)v.y, (f16)v.z, (f16)v.w};
        *(f16x4*)&T[cr][m4] = h;
    }
    __syncthreads();
    const int m_r = tid >> 2, cq = (tid & 3) * 16;
    f16 buf[16];
    #pragma unroll
    for (int j = 0; j < 16; ++j) buf[j] = T[cq + j][m_r];
    f16* dst = xt + ((size_t)b * NN + m0 + m_r) * CC + c0 + cq;
    *(f16x8*)dst       = *(f16x8*)&buf[0];
    *(f16x8*)(dst + 8) = *(f16x8*)&buf[8];
}

// ---------------------------------------------------------------------------
// qkv_mfma R10 (unchanged, verified): gload_lds staging + LDS epilogue.
// Q pre-scaled by log2(e) (attn softmax runs in exp2 domain).
// ---------------------------------------------------------------------------
__global__ __launch_bounds__(256) void qkv_mfma(
    const f16*  __restrict__ xt,     // [B*N][C]
    const f16*  __restrict__ Wh,     // [3C][C]
    const float* __restrict__ h_pos, // [L][C]
    const float* __restrict__ w_pos, // [L][C]
    f16* __restrict__ Qh, f16* __restrict__ Kh, f16* __restrict__ Vt)
{
    __shared__ f16 SM[2 * 128 * 64];   // Xs | Ws, reused as epilogue scratch
    f16* Xs = SM;
    f16* Ws = SM + 128 * 64;

    const int tid  = threadIdx.x;
    const int wave = tid >> 6, lane = tid & 63;
    const int ln = lane & 15, quad = lane >> 4;

    const unsigned bid  = blockIdx.x;
    const unsigned xcd  = bid & 7;
    const unsigned slot = bid >> 3;            // 0..383
    const unsigned ot   = slot % 12u;
    const unsigned mt   = xcd * 32u + slot / 12u;
    const int o0  = (int)ot * 128;
    const int mg0 = (int)mt * 128;
    const int mw = (wave & 1) * 64, ow = (wave >> 1) * 64;

    f32x4 acc[4][4];
    #pragma unroll
    for (int ia = 0; ia < 4; ++ia)
        #pragma unroll
        for (int ib = 0; ib < 4; ++ib) acc[ia][ib] = (f32x4){0.f, 0.f, 0.f, 0.f};

    const int sr = wave * 32 + (lane >> 3);
    const int sc = (lane & 7) * 8;
    const f16* xg = xt + (size_t)(mg0 + sr) * CC + sc;
    const f16* wg = Wh + (size_t)(o0  + sr) * CC + sc;
    f16* xl = &Xs[(wave * 32) * 64];
    f16* wl = &Ws[(wave * 32) * 64];

    for (int ct = 0; ct < 8; ++ct) {
        const int c0 = ct * 64;
        __syncthreads();
        #pragma unroll
        for (int i = 0; i < 4; ++i) {
            gload16(xg + (size_t)i * 8 * CC + c0, xl + i * 8 * 64);
            gload16(wg + (size_t)i * 8 * CC + c0, wl + i * 8 * 64);
        }
        __syncthreads();   // drains vmcnt(0): tile visible
        #pragma unroll
        for (int ks = 0; ks < 2; ++ks) {
            f16x8 a[4], bf[4];
            #pragma unroll
            for (int f = 0; f < 4; ++f) {
                a[f]  = *(const f16x8*)&Xs[(mw + f * 16 + ln) * 64 + ks * 32 + quad * 8];
                bf[f] = *(const f16x8*)&Ws[(ow + f * 16 + ln) * 64 + ks * 32 + quad * 8];
            }
            #pragma unroll
            for (int ia = 0; ia < 4; ++ia)
                #pragma unroll
                for (int ib = 0; ib < 4; ++ib)
                    acc[ia][ib] = __builtin_amdgcn_mfma_f32_16x16x32_f16(
                        a[ia], bf[ib], acc[ia][ib], 0, 0, 0);
        }
    }

    __syncthreads();   // all waves done with Xs/Ws; safe to reuse as scratch
    f16* Ep = SM + wave * 4096;   // 8 KB per wave

    const int region = o0 >> 9;             // 0=Q, 1=K, 2=V
    const int ob = o0 + ow;
    const int p  = (ob >> 6) & 7;
    const int b  = mg0 >> 10;
    const int n0 = (mg0 & 1023) + mw;

    if (region < 2) {
        f16* dst = (region == 0) ? Qh : Kh;
        const size_t hb = (size_t)(b * HEADS + p) * NN * DD;
        #pragma unroll
        for (int ph = 0; ph < 2; ++ph) {
            #pragma unroll
            for (int ibl = 0; ibl < 2; ++ibl) {
                const int ib = ph * 2 + ibl;
                const int d  = ib * 16 + ln;
                const int dl = ibl * 16 + ln;
                #pragma unroll
                for (int ia = 0; ia < 4; ++ia) {
                    #pragma unroll
                    for (int r = 0; r < 4; ++r) {
                        const int nl = ia * 16 + quad * 4 + r;
                        float v = acc[ia][ib][r];
                        if (region == 0) {
                            v *= 1.44269504f;   // log2(e)
                        } else {
                            const int n = n0 + nl;
                            const int c = p * DD + d;
                            v += h_pos[(n >> 5) * CC + c] + w_pos[(n & 31) * CC + c];
                        }
                        Ep[nl * 34 + dl] = (f16)v;
                    }
                }
            }
            wavefence();
            #pragma unroll
            for (int j = 0; j < 4; ++j) {
                const int nl = (lane >> 2) + 16 * j;
                const int dc = (lane & 3) * 8;
                f16x8 row = *(const f16x8*)&Ep[nl * 34 + dc];
                *(f16x8*)(dst + hb + (size_t)(n0 + nl) * DD + ph * 32 + dc) = row;
            }
            wavefence();
        }
    } else {
        const size_t vb = (size_t)(b * HEADS + p) * DD * NN;
        #pragma unroll
        for (int ph = 0; ph < 2; ++ph) {
            #pragma unroll
            for (int ibl = 0; ibl < 2; ++ibl) {
                const int ib = ph * 2 + ibl;
                const int dl = ibl * 16 + ln;
                #pragma unroll
                for (int ia = 0; ia < 4; ++ia) {
                    const int nl = ia * 16 + quad * 4;
                    f16x4 pk = {(f16)acc[ia][ib][0], (f16)acc[ia][ib][1],
                                (f16)acc[ia][ib][2], (f16)acc[ia][ib][3]};
                    *(f16x4*)&Ep[dl * 68 + nl] = pk;
                }
            }
            wavefence();
            #pragma unroll
            for (int j = 0; j < 4; ++j) {
                const int dl = (lane >> 3) + 8 * j;
                const int nc = (lane & 7) * 8;
                f16x8 row = *(const f16x8*)&Ep[dl * 68 + nc];
                *(f16x8*)(Vt + vb + (size_t)(ph * 32 + dl) * NN + n0 + nc) = row;
            }
            wavefence();
        }
    }
}

// ---------------------------------------------------------------------------
// attn_kernel R15 = R14 math (32x32x16 MFMA, in-register P, verified) with
// 4-wave blocks sharing one K/V LDS tile:
//  * stage writes per thread halve (2 b128 per matrix, was 4);
//  * prefetch regs halve (kr/vr[2], -16 VGPR);
//  * LDS 19.4 KB now serves 4 waves -> residency cap rises;
//  * grid 2048 x 256 thr (same total waves, same work per wave).
// ---------------------------------------------------------------------------
#define KST 76

__global__ __launch_bounds__(256) void attn_kernel(
    const f16* __restrict__ Qh, const f16* __restrict__ Kh,
    const f16* __restrict__ Vt, float* __restrict__ out)
{
    __shared__ f16 KS [64 * KST];
    __shared__ f16 VtS[64 * KST];

    const int tid  = threadIdx.x;
    const int wave = tid >> 6;          // 0..3
    const int lane = tid & 63;
    const int l31  = lane & 31;
    const int h    = lane >> 5;

    // XCD swizzle: grid 2048 = 8 XCDs x 32 (b,p)-groups x 8 qt.
    const unsigned bid  = blockIdx.x;
    const unsigned xcd  = bid & 7;
    const unsigned slot = bid >> 3;              // 0..255
    const int qt = (int)(slot & 7u);
    const unsigned g = xcd * 32u + (slot >> 3);  // 0..255
    const int b = (int)(g >> 3);
    const int p = (int)(g & 7u);
    const size_t hb = (size_t)(b * HEADS + p) * NN * DD;

    // Q B-frags: col q = l31, k = 16s + 8h + j  (4 frags cover d=64).
    const int qbase = qt * 128 + wave * 32;
    f16x8 qf[4];
    #pragma unroll
    for (int s = 0; s < 4; ++s)
        qf[s] = *(const f16x8*)(Qh + hb + (size_t)(qbase + l31) * DD + s * 16 + h * 8);

    // O accumulators: C[row=d][col=q]; oA: d 0..31, oB: d 32..63.
    f32x16 oA = {0.f,0.f,0.f,0.f,0.f,0.f,0.f,0.f,0.f,0.f,0.f,0.f,0.f,0.f,0.f,0.f};
    f32x16 oB = oA;
    float lrun = 0.f;
    float mrun = -__builtin_inff();
    const float THR = 11.5416f;   // 8 nats in log2 units

    // Staging: thread covers row tr = tid>>2, 16-f16 chunk tc = (tid&3)*16.
    const int tr = tid >> 2, tc = (tid & 3) * 16;
    f16x8 kr[2], vr[2];
    #pragma unroll
    for (int k = 0; k < 2; ++k) {
        kr[k] = *(const f16x8*)(Kh + hb + (size_t)tr * DD + tc + k * 8);
        vr[k] = *(const f16x8*)(Vt + hb + (size_t)tr * NN + tc + k * 8);
    }

    for (int kt = 0; kt < 16; ++kt) {
        __syncthreads();   // B1
        #pragma unroll
        for (int k = 0; k < 2; ++k) {
            *(f16x8*)&KS [tr * KST + tc + k * 8] = kr[k];
            *(f16x8*)&VtS[tr * KST + tc + k * 8] = vr[k];
        }
        if (kt < 15) {   // T14: next-tile loads in flight across compute
            #pragma unroll
            for (int k = 0; k < 2; ++k) {
                kr[k] = *(const f16x8*)(Kh + hb + (size_t)((kt + 1) * 64 + tr) * DD + tc + k * 8);
                vr[k] = *(const f16x8*)(Vt + hb + (size_t)tr * NN + (kt + 1) * 64 + tc + k * 8);
            }
        }
        __syncthreads();   // B2

        // QK^T: sA = S^T[keys 0..31][q], sB = [keys 32..63][q]  (log2 domain)
        f32x16 sA = {0.f,0.f,0.f,0.f,0.f,0.f,0.f,0.f,0.f,0.f,0.f,0.f,0.f,0.f,0.f,0.f};
        f32x16 sB = sA;
        #pragma unroll
        for (int s = 0; s < 4; ++s) {
            f16x8 a0 = *(const f16x8*)&KS[(l31)      * KST + s * 16 + h * 8];
            f16x8 a1 = *(const f16x8*)&KS[(32 + l31) * KST + s * 16 + h * 8];
            sA = __builtin_amdgcn_mfma_f32_32x32x16_f16(a0, qf[s], sA, 0, 0, 0);
            sB = __builtin_amdgcn_mfma_f32_32x32x16_f16(a1, qf[s], sB, 0, 0, 0);
        }

        // Row max for q=l31: 31 in-reg fmax + 1 cross-half permlane swap.
        float mx = sA[0];
        #pragma unroll
        for (int i = 1; i < 16; ++i) mx = fmaxf(mx, sA[i]);
        #pragma unroll
        for (int i = 0; i < 16; ++i) mx = fmaxf(mx, sB[i]);
        mx = xhalf_max(mx);

        // T13 defer-max.
        if (__any(mx > mrun + THR)) {
            const float mnew = fmaxf(mrun, mx);
            const float alpha = __builtin_amdgcn_exp2f(mrun - mnew);  // 0 first tile
            mrun = mnew;
            lrun *= alpha;
            #pragma unroll
            for (int i = 0; i < 16; ++i) { oA[i] *= alpha; oB[i] *= alpha; }
        }

        // PV: 4 steps of 16 keys; P built in-register (T12), zero DS for P.
        float lsum = 0.f;
        #pragma unroll
        for (int s = 0; s < 4; ++s) {
            const f32x16& sk = (s < 2) ? sA : sB;
            const int base = (s & 1) * 8;
            const float e0 = __builtin_amdgcn_exp2f(sk[base + 0] - mrun);
            const float e1 = __builtin_amdgcn_exp2f(sk[base + 1] - mrun);
            const float e2 = __builtin_amdgcn_exp2f(sk[base + 2] - mrun);
            const float e3 = __builtin_amdgcn_exp2f(sk[base + 3] - mrun);
            const float e4 = __builtin_amdgcn_exp2f(sk[base + 4] - mrun);
            const float e5 = __builtin_amdgcn_exp2f(sk[base + 5] - mrun);
            const float e6 = __builtin_amdgcn_exp2f(sk[base + 6] - mrun);
            const float e7 = __builtin_amdgcn_exp2f(sk[base + 7] - mrun);
            lsum += ((e0 + e1) + (e2 + e3)) + ((e4 + e5) + (e6 + e7));
            unsigned d00 = __builtin_bit_cast(unsigned, __builtin_amdgcn_cvt_pkrtz(e0, e1));
            unsigned d01 = __builtin_bit_cast(unsigned, __builtin_amdgcn_cvt_pkrtz(e2, e3));
            unsigned d10 = __builtin_bit_cast(unsigned, __builtin_amdgcn_cvt_pkrtz(e4, e5));
            unsigned d11 = __builtin_bit_cast(unsigned, __builtin_amdgcn_cvt_pkrtz(e6, e7));
            pl32swap(d00, d10);   // h=0: keys {0,1},{4,5}; h=1: {8,9},{12,13} (+16s)
            pl32swap(d01, d11);   // h=0: keys {2,3},{6,7}; h=1: {10,11},{14,15}
            u32x4 pu = {d00, d01, d10, d11};
            f16x8 pb = __builtin_bit_cast(f16x8, pu);   // B[k=8h+j][q=l31]
            f16x8 v0 = *(const f16x8*)&VtS[(l31)      * KST + s * 16 + h * 8];
            f16x8 v1 = *(const f16x8*)&VtS[(32 + l31) * KST + s * 16 + h * 8];
            oA = __builtin_amdgcn_mfma_f32_32x32x16_f16(v0, pb, oA, 0, 0, 0);
            oB = __builtin_amdgcn_mfma_f32_32x32x16_f16(v1, pb, oB, 0, 0, 0);
        }
        lrun += xhalf_sum(lsum);
    }

    // Epilogue: lane holds O[d][q=l31], d = dblk*32 + (reg&3)+8*(reg>>2)+4h.
    const float inv = 1.0f / lrun;
    const int nq = qbase + l31;
    float* ob = out + ((size_t)b * CC + p * DD) * NN + nq;
    #pragma unroll
    for (int reg = 0; reg < 16; ++reg) {
        const int dr = (reg & 3) + 8 * (reg >> 2) + 4 * h;
        ob[(size_t)dr * NN]        = oA[reg] * inv;
        ob[(size_t)(32 + dr) * NN] = oB[reg] * inv;
    }
}

extern "C" void kernel_launch(void* const* d_in, const int* in_sizes, int n_in,
                              void* d_out, int out_size, void* d_ws, size_t ws_size,
                              hipStream_t stream) {
    const float* x     = (const float*)d_in[0];
    const float* qkv_w = (const float*)d_in[1];
    const float* h_pos = (const float*)d_in[2];
    const float* w_pos = (const float*)d_in[3];
    float* out = (float*)d_out;

    const size_t PT = (size_t)BB * HEADS * NN * DD;  // 16,777,216 elems
    f16* xt = (f16*)d_ws;
    f16* Qh = xt + PT;
    f16* Kh = Qh + PT;
    f16* Vt = Kh + PT;
    f16* Wh = Vt + PT;   // 3C*C = 786,432 f16; total ~135.7 MB (fits)

    wconv<<<dim3(3 * CC * CC / (256 * 8)), 256, 0, stream>>>(qkv_w, Wh);
    prep_x<<<dim3(CC / 64, NN / 64, BB), 256, 0, stream>>>(x, xt);
    qkv_mfma<<<dim3(3072), 256, 0, stream>>>(xt, Wh, h_pos, w_pos, Qh, Kh, Vt);
    attn_kernel<<<dim3(2048), 256, 0, stream>>>(Qh, Kh, Vt, out);
}